// Round 1
// baseline (3889.724 us; speedup 1.0000x reference)
//
#include <hip/hip_runtime.h>
#include <math.h>

// LSTM anomaly scan, B=256 T=1024 I=8 H=164 O=1, WL=0, THRESH=0.1.
// One block (704 thr = 11 waves) per batch element, sequential t-loop.
// Thread j owns gate row j. Register-pressure-disciplined rewrite:
//  - W_ih (8 f) + W_hh cols 0..103 (26 float4) per-thread in VGPRs,
//    asm-pinned ("+v") so the allocator cannot rematerialize them
//    (previous version reported VGPR_Count=80 => weights were NOT resident).
//  - W_hh cols 104..163 in 15 LDS planes, 3-deep rotating ds_read prefetch.
//  - tanh rows pre-doubled at stage time => single sigmoid activation path
//    (tanh = 2*sigma(2x)-1), overflow-safe, no clamp, no divergent dual eval.
//  - divisions via v_rcp + 1 Newton step (~0.5ulp) instead of IEEE div.
//  - gates packed [unit][4] in LDS: epilogue reads are 3x ds_read_b128.
//  - h broadcast via v_readlane of redundant per-wave state (units lane,
//    64+lane, 128+lane); ONE barrier/step, double-buffered gate planes.

typedef __attribute__((ext_vector_type(4))) float f4;

namespace {
constexpr int kB = 256;
constexpr int kT = 1024;
constexpr int kI = 8;
constexpr int kH = 164;
constexpr int kG = 4 * kH;                 // 656
constexpr int kThreads = 704;              // 11 waves
constexpr int kRegK = 104;                 // W_hh cols in VGPRs (26 float4)
constexpr int kTailC = (kH - kRegK) / 4;   // 15 LDS planes (cols 104..163)
constexpr float kThresh = 0.1f;

__device__ __forceinline__ float rlane(float v, int l) {
    return __int_as_float(__builtin_amdgcn_readlane(__float_as_int(v), l));
}
__device__ __forceinline__ float hb(float h0, float h1, float h2, int k) {
    return (k < 64) ? rlane(h0, k)
         : (k < 128) ? rlane(h1, k - 64)
                     : rlane(h2, k - 128);
}
template <int CTRL>
__device__ __forceinline__ float dpp_add(float x) {
    int t = __builtin_amdgcn_update_dpp(0, __float_as_int(x), CTRL, 0xf, 0xf, true);
    return __int_as_float(t);
}
// full-wave sum, result broadcast via lane 63
__device__ __forceinline__ float wave_sum(float x) {
    x += dpp_add<0x111>(x);   // row_shr:1
    x += dpp_add<0x112>(x);   // row_shr:2
    x += dpp_add<0x114>(x);   // row_shr:4
    x += dpp_add<0x118>(x);   // row_shr:8
    x += dpp_add<0x142>(x);   // row_bcast:15
    x += dpp_add<0x143>(x);   // row_bcast:31
    return rlane(x, 63);
}
// rcp + one Newton iteration: ~0.5 ulp at 3 instructions
__device__ __forceinline__ float fast_rcp(float d) {
    float r = __builtin_amdgcn_rcpf(d);
    float e = fmaf(-d, r, 1.0f);
    return fmaf(r, e, r);
}
// tanh(x) = 2*sigma(2x) - 1; exp/rcp saturate gracefully, no clamp needed
__device__ __forceinline__ float tanh_c(float x) {
    float e = __expf(-2.0f * x);
    return fmaf(2.0f, fast_rcp(1.0f + e), -1.0f);
}
} // namespace

__global__ __launch_bounds__(kThreads, 3) void lstm_anom_kernel(
    const float* __restrict__ x,     // (B,T,I)
    const float* __restrict__ Wih,   // (4H,I)
    const float* __restrict__ Whh,   // (4H,H)
    const float* __restrict__ bih,   // (4H)
    const float* __restrict__ bhh,   // (4H)
    const float* __restrict__ Wout,  // (1,H)
    const float* __restrict__ bout,  // (1)
    float* __restrict__ out)         // preds (B,T) then flags (B,T)
{
    __shared__ f4    wp[kTailC * kG];   // 15*656*16 = 157440 B
    __shared__ float g4[2][kH][4];      // 5248 B  (total 162688 B)

    const int tid  = threadIdx.x;
    const int lane = tid & 63;
    const int b    = blockIdx.x;
    const int jj   = (tid < kG) ? tid : (kG - 1);
    const int gate = jj / kH;             // 0=i 1=f 2=g 3=o
    const int unit = jj - gate * kH;      // 0..163
    const bool is_tanh = (gate == 2);
    const float wscl = is_tanh ? 2.0f : 1.0f;

    // ---- stage W_hh tail planes (cols kRegK..163), tanh rows pre-doubled ----
    for (int i = tid; i < kTailC * kG; i += kThreads) {
        const int c = i % kTailC;         // c inner => coalesced global reads
        const int r = i / kTailC;
        f4 v = *(const f4*)(Whh + (size_t)r * kH + kRegK + 4 * c);
        if (r >= 2 * kH && r < 3 * kH) v *= 2.0f;
        wp[c * kG + r] = v;
    }

    // ---- per-thread resident weights, asm-pinned against remat/spill ----
    f4 wih0 = ((const f4*)(Wih + (size_t)jj * kI))[0] * wscl;
    f4 wih1 = ((const f4*)(Wih + (size_t)jj * kI))[1] * wscl;
    asm volatile("" : "+v"(wih0), "+v"(wih1));
    f4 whh[kRegK / 4];
    #pragma unroll
    for (int k = 0; k < kRegK / 4; ++k) {
        whh[k] = ((const f4*)(Whh + (size_t)jj * kH))[k] * wscl;
        asm volatile("" : "+v"(whh[k]));
    }
    const float bsum = (bih[jj] + bhh[jj]) * wscl;
    const int   u2   = (lane < kH - 128) ? (128 + lane) : (kH - 1); // clamp
    float wo0 = Wout[lane];
    float wo1 = Wout[64 + lane];
    float wo2 = (128 + lane < kH) ? Wout[128 + lane] : 0.0f;        // kills dup
    asm volatile("" : "+v"(wo0), "+v"(wo1), "+v"(wo2));
    const float bo = bout[0];

    // redundant per-wave state: units lane, 64+lane, u2
    float vc0 = 0.f, vc1 = 0.f, vc2 = 0.f;
    float vh0 = 0.f, vh1 = 0.f, vh2 = 0.f;
    float pred = 0.f;

    const float* xb = x + (size_t)b * kT * kI;
    float* pred_out = out + (size_t)b * kT;
    float* flag_out = out + (size_t)kB * kT + (size_t)b * kT;

    // 3 LDS base pointers keep all tail ds_read offsets within imm range
    const f4* wt0 = wp + jj;
    const f4* wt5 = wp + 5 * kG + jj;
    const f4* wtA = wp + 10 * kG + jj;

    f4 xa = ((const f4*)xb)[0];
    f4 xc = ((const f4*)xb)[1];

    __syncthreads();

    for (int t = 0; t < kT; ++t) {
        const bool  anom = (t > 0) && (fabsf(pred - xa.x) > kThresh);
        const float x0e  = anom ? pred : xa.x;

        // ---- x-part: 4 independent accumulators; xa/xc die here ----
        float a0 = fmaf(x0e, wih0.x, bsum);
        float a1 = xa.y * wih0.y;
        float a2 = xa.z * wih0.z;
        float a3 = xa.w * wih0.w;
        a0 = fmaf(xc.x, wih1.x, a0);
        a1 = fmaf(xc.y, wih1.y, a1);
        a2 = fmaf(xc.z, wih1.z, a2);
        a3 = fmaf(xc.w, wih1.w, a3);

        // prefetch x[t+1] now: whole FMA loop hides the HBM latency
        const f4* nx = (const f4*)(xb + (size_t)((t + 1 < kT) ? t + 1 : t) * kI);
        f4 na = nx[0];
        f4 nc = nx[1];

        // LDS tail prefetch, 3 deep; latency hides under register groups
        f4 t0 = wt0[0];
        f4 t1 = wt0[kG];
        f4 t2 = wt0[2 * kG];

        #define GRP(W, KB) \
            a0 = fmaf(hb(vh0, vh1, vh2, (KB) + 0), (W).x, a0); \
            a1 = fmaf(hb(vh0, vh1, vh2, (KB) + 1), (W).y, a1); \
            a2 = fmaf(hb(vh0, vh1, vh2, (KB) + 2), (W).z, a2); \
            a3 = fmaf(hb(vh0, vh1, vh2, (KB) + 3), (W).w, a3);

        #pragma unroll
        for (int kk = 0; kk < kRegK / 4; ++kk) {
            GRP(whh[kk], kk * 4);
        }
        #pragma unroll
        for (int c = 0; c < kTailC; ++c) {
            f4 w;
            if (c % 3 == 0) w = t0; else if (c % 3 == 1) w = t1; else w = t2;
            const int cn = c + 3;
            if (cn < kTailC) {
                const f4 ld = (cn < 5)  ? wt0[cn * kG]
                            : (cn < 10) ? wt5[(cn - 5) * kG]
                                        : wtA[(cn - 10) * kG];
                if (c % 3 == 0) t0 = ld; else if (c % 3 == 1) t1 = ld; else t2 = ld;
            }
            GRP(w, kRegK + c * 4);
        }
        #undef GRP

        // ---- unified activation: rows pre-doubled => sigma path only ----
        const float acc = (a0 + a1) + (a2 + a3);
        const float ee  = __expf(-acc);
        const float yy  = fast_rcp(1.0f + ee);
        const float av  = is_tanh ? fmaf(2.0f, yy, -1.0f) : yy;

        if (tid < kG) g4[t & 1][unit][gate] = av;
        __syncthreads();

        // ---- redundant cell/h update in every wave (no 2nd barrier) ----
        const f4 Ga = *(const f4*)&g4[t & 1][lane][0];
        const f4 Gb = *(const f4*)&g4[t & 1][64 + lane][0];
        const f4 Gc = *(const f4*)&g4[t & 1][u2][0];

        vc0 = fmaf(Ga.y, vc0, Ga.x * Ga.z);  vh0 = Ga.w * tanh_c(vc0);
        vc1 = fmaf(Gb.y, vc1, Gb.x * Gb.z);  vh1 = Gb.w * tanh_c(vc1);
        vc2 = fmaf(Gc.y, vc2, Gc.x * Gc.z);  vh2 = Gc.w * tanh_c(vc2);

        // ---- pred (identical in every wave; DPP reduce, VALU only) ----
        const float p = fmaf(vh0, wo0, fmaf(vh1, wo1, vh2 * wo2));
        pred = wave_sum(p) + bo;

        if (tid == 0) {
            pred_out[t] = pred;
            flag_out[t] = anom ? 1.0f : 0.0f;
        }
        xa = na;
        xc = nc;
    }
}

extern "C" void kernel_launch(void* const* d_in, const int* in_sizes, int n_in,
                              void* d_out, int out_size, void* d_ws, size_t ws_size,
                              hipStream_t stream) {
    const float* x    = (const float*)d_in[0];
    const float* Wih  = (const float*)d_in[1];
    const float* Whh  = (const float*)d_in[2];
    const float* bih  = (const float*)d_in[3];
    const float* bhh  = (const float*)d_in[4];
    const float* Wout = (const float*)d_in[5];
    const float* bout = (const float*)d_in[6];
    lstm_anom_kernel<<<dim3(kB), dim3(kThreads), 0, stream>>>(
        x, Wih, Whh, bih, bhh, Wout, bout, (float*)d_out);
}